// Round 1
// baseline (1387.850 us; speedup 1.0000x reference)
//
#include <hip/hip_runtime.h>
#include <math.h>

// Problem constants (from reference setup_inputs)
#define B_   2
#define L_   8192
#define H_   16
#define D_   64
#define C_   1024
#define NC_  8          // L / C
#define BQ_  256        // q-rows per block (== blockDim.x, 1 row / thread)
#define BK_  16         // k-rows per LDS tile
#define QT_  4          // C / BQ_
// log2(10000)/32 : inv_freq[f] = 2^(-f * this)
#define LOG2B_OVER_HALFDIM 0.41524101186098314f

__global__ __launch_bounds__(256, 2)
void chunked_attn_fp32(const float* __restrict__ qg, const float* __restrict__ kg,
                       const float* __restrict__ vg, const int* __restrict__ sidx,
                       float* __restrict__ outg)
{
    const int t   = threadIdx.x;
    const int bid = blockIdx.x;
    const int qt  = bid & (QT_ - 1);
    const int h   = (bid >> 2) & (H_ - 1);
    const int n   = (bid >> 6) & (NC_ - 1);
    const int b   = bid >> 9;

    const int start = sidx[0];
    const int p0    = start + n * C_;      // absolute position of chunk row 0

    const int  qc = qt * BQ_ + t;          // this thread's row within the chunk
    const long lq = (long)n * C_ + qc;     // row within the sequence

    const float* qrow = qg + (((long)b * L_ + lq) * H_ + h) * D_;

    // ---- load q row into registers, apply RoPE ----
    float qr[D_];
    #pragma unroll
    for (int i = 0; i < D_ / 4; ++i) {
        float4 f = *(const float4*)(qrow + i * 4);
        qr[i*4+0] = f.x; qr[i*4+1] = f.y; qr[i*4+2] = f.z; qr[i*4+3] = f.w;
    }
    {
        const float fp = (float)(p0 + qc);
        #pragma unroll
        for (int f = 0; f < 32; ++f) {
            float invf = exp2f(-(float)f * LOG2B_OVER_HALFDIM);
            float sn, cs;
            sincosf(fp * invf, &sn, &cs);
            float a = qr[f], bb = qr[f + 32];
            qr[f]      = a * cs - bb * sn;   // x1*cos - x2*sin
            qr[f + 32] = bb * cs + a * sn;   // x2*cos + x1*sin
        }
    }

    // ---- per-thread constants for cooperative K-RoPE (2 pairs / thread) ----
    const int   f01    = t & 31;                       // freq index, same for both pairs
    const float invf_k = exp2f(-(float)f01 * LOG2B_OVER_HALFDIM);

    const float* kbase = kg + (((long)b * L_ + (long)n * C_) * H_ + h) * D_;
    const float* vbase = vg + (((long)b * L_ + (long)n * C_) * H_ + h) * D_;

    __shared__ float Kl[BK_ * D_];
    __shared__ float Vl[BK_ * D_];

    float O[D_];
    #pragma unroll
    for (int i = 0; i < D_; ++i) O[i] = 0.f;
    float m = -INFINITY, l = 0.f;

    const int nkt    = (qt + 1) * (BQ_ / BK_);  // k-tiles this block must cover
    const int rstage = t >> 4;                  // staging: row 0..15
    const int cstage = (t & 15) * 4;            // staging: float4 column

    for (int kt = 0; kt < nkt; ++kt) {
        const int krow0 = kt * BK_;

        __syncthreads();   // previous tile fully consumed before restaging
        {
            const long goff = (long)(krow0 + rstage) * (H_ * D_) + cstage;
            float4 kf = *(const float4*)(kbase + goff);
            float4 vf = *(const float4*)(vbase + goff);
            *(float4*)(&Kl[rstage * D_ + cstage]) = kf;
            *(float4*)(&Vl[rstage * D_ + cstage]) = vf;
        }
        __syncthreads();

        // in-LDS RoPE on K tile: 16 rows x 32 pairs = 512 pairs, 2/thread
        #pragma unroll
        for (int i = 0; i < 2; ++i) {
            const int r = i * 8 + (t >> 5);
            float sn, cs;
            sincosf((float)(p0 + krow0 + r) * invf_k, &sn, &cs);
            float a  = Kl[r * D_ + f01];
            float bb = Kl[r * D_ + f01 + 32];
            Kl[r * D_ + f01]      = a * cs - bb * sn;
            Kl[r * D_ + f01 + 32] = bb * cs + a * sn;
        }
        __syncthreads();

        // ---- scores for this tile (wave-uniform LDS reads -> broadcast) ----
        float sv[BK_];
        #pragma unroll
        for (int kj = 0; kj < BK_; ++kj) {
            float acc = 0.f;
            #pragma unroll
            for (int d = 0; d < D_; ++d) acc = fmaf(qr[d], Kl[kj * D_ + d], acc);
            sv[kj] = (krow0 + kj <= qc) ? acc : -INFINITY;
        }

        float tmax = -INFINITY;
        #pragma unroll
        for (int kj = 0; kj < BK_; ++kj) tmax = fmaxf(tmax, sv[kj]);
        float mnew = fmaxf(m, tmax);

        if (mnew != -INFINITY) {   // skip tiles that are fully masked so far
            float alpha = __expf(m - mnew);   // m=-inf -> 0, correct
            l *= alpha;
            #pragma unroll
            for (int d = 0; d < D_; ++d) O[d] *= alpha;
            #pragma unroll
            for (int kj = 0; kj < BK_; ++kj) {
                float p = __expf(sv[kj] - mnew);   // masked -> exp(-inf)=0
                l += p;
                #pragma unroll
                for (int d = 0; d < D_; ++d) O[d] = fmaf(p, Vl[kj * D_ + d], O[d]);
            }
            m = mnew;
        }
    }

    // ---- normalize + store ----
    const float inv_l = 1.0f / l;   // diagonal always present -> l >= 1
    float* orow = outg + (((long)b * L_ + lq) * H_ + h) * D_;
    #pragma unroll
    for (int i = 0; i < D_ / 4; ++i) {
        float4 f;
        f.x = O[i*4+0] * inv_l;
        f.y = O[i*4+1] * inv_l;
        f.z = O[i*4+2] * inv_l;
        f.w = O[i*4+3] * inv_l;
        *(float4*)(orow + i * 4) = f;
    }
}

extern "C" void kernel_launch(void* const* d_in, const int* in_sizes, int n_in,
                              void* d_out, int out_size, void* d_ws, size_t ws_size,
                              hipStream_t stream) {
    const float* q    = (const float*)d_in[0];
    const float* k    = (const float*)d_in[1];
    const float* v    = (const float*)d_in[2];
    const int*   sidx = (const int*)d_in[3];
    float*       out  = (float*)d_out;

    dim3 grid(B_ * NC_ * H_ * QT_);   // 1024 blocks: (b, n, h, qt)
    dim3 block(256);
    chunked_attn_fp32<<<grid, block, 0, stream>>>(q, k, v, sidx, out);
}

// Round 2
// 356.244 us; speedup vs baseline: 3.8958x; 3.8958x over previous
//
#include <hip/hip_runtime.h>
#include <math.h>

typedef _Float16 half8 __attribute__((ext_vector_type(8)));
typedef _Float16 half4 __attribute__((ext_vector_type(4)));
typedef float    floatx4 __attribute__((ext_vector_type(4)));

#define B_   2
#define L_   8192
#define H_   16
#define D_   64
#define C_   1024
#define NC_  8
#define QT_  4
#define HD_  (H_ * D_)        // global row stride = 1024 floats
#define KSTR 72               // Kl row stride (f16): 144 B -> 2-way banks on b128
#define VSTR 40               // Vt row stride (f16): 80 B
#define PSTR 40               // Pl row stride (f16): 80 B
#define LOG2B 0.41524101186098314f   // log2(10000)/32

__device__ __forceinline__ float rormax16(float v) {
    // max across each 16-lane row via DPP row_ror (VALU-rate, no LDS)
    int x;
    x = __builtin_amdgcn_mov_dpp(__float_as_int(v), 0x121, 0xf, 0xf, true); v = fmaxf(v, __int_as_float(x));
    x = __builtin_amdgcn_mov_dpp(__float_as_int(v), 0x122, 0xf, 0xf, true); v = fmaxf(v, __int_as_float(x));
    x = __builtin_amdgcn_mov_dpp(__float_as_int(v), 0x124, 0xf, 0xf, true); v = fmaxf(v, __int_as_float(x));
    x = __builtin_amdgcn_mov_dpp(__float_as_int(v), 0x128, 0xf, 0xf, true); v = fmaxf(v, __int_as_float(x));
    return v;
}

__global__ __launch_bounds__(256, 2)
void attn_mfma_f16(const float* __restrict__ qg, const float* __restrict__ kg,
                   const float* __restrict__ vg, const int* __restrict__ sidx,
                   float* __restrict__ outg)
{
    __shared__ __align__(16) _Float16 Kl[32 * KSTR];
    __shared__ __align__(16) _Float16 Vt[64 * VSTR];
    __shared__ __align__(16) _Float16 Pl[4][64 * PSTR];

    const int t  = threadIdx.x;
    const int w  = t >> 6;         // wave 0..3
    const int l  = t & 63;
    const int lg = l >> 4;         // 16-lane group 0..3
    const int ln = l & 15;

    const int bid = blockIdx.x;
    const int qt = bid & 3;
    const int h  = (bid >> 2) & 15;
    const int n  = (bid >> 6) & 7;
    const int b  = bid >> 9;

    const int p0 = sidx[0] + n * C_;          // absolute position of chunk row 0
    const int qb = qt * 256 + w * 64;         // wave's q base within chunk

    const long bhbase = ((long)b * L_ + (long)n * C_) * HD_ + (long)h * D_;
    const float* kbase = kg + bhbase;
    const float* vbase = vg + bhbase;

    // ---- Q fragments (A-layout) with RoPE, fp16 ----
    // aq[rt][kt]: lane holds Q[qb+rt*16+ln][kt*32 + lg*8 + j], j=0..7
    half8 aq[4][2];
    const int d0 = lg * 8;
    #pragma unroll
    for (int rt = 0; rt < 4; ++rt) {
        const int qr = qb + rt * 16 + ln;
        const float* qp = qg + bhbase + (long)qr * HD_;
        float4 f0 = *(const float4*)(qp + d0);
        float4 f1 = *(const float4*)(qp + d0 + 4);
        float4 g0 = *(const float4*)(qp + d0 + 32);
        float4 g1 = *(const float4*)(qp + d0 + 36);
        float x[8] = {f0.x,f0.y,f0.z,f0.w,f1.x,f1.y,f1.z,f1.w};
        float y[8] = {g0.x,g0.y,g0.z,g0.w,g1.x,g1.y,g1.z,g1.w};
        const float pos = (float)(p0 + qr);
        #pragma unroll
        for (int j = 0; j < 8; ++j) {
            float invf = exp2f(-(float)(d0 + j) * LOG2B);
            float sn, cs; __sincosf(pos * invf, &sn, &cs);
            aq[rt][0][j] = (_Float16)(x[j] * cs - y[j] * sn);
            aq[rt][1][j] = (_Float16)(y[j] * cs + x[j] * sn);
        }
    }

    // ---- accumulators ----
    floatx4 O[4][4];      // [rt][dvt], C-layout: row = lg*4+reg, col = dvt*16+ln
    floatx4 Ol[4];        // l accumulator via ones-MFMA (all 16 cols equal rowsum)
    float   mr[4][4];     // running row max, row = lg*4+reg
    #pragma unroll
    for (int rt = 0; rt < 4; ++rt) {
        Ol[rt] = (floatx4){0.f, 0.f, 0.f, 0.f};
        #pragma unroll
        for (int dt = 0; dt < 4; ++dt) O[rt][dt] = (floatx4){0.f, 0.f, 0.f, 0.f};
        #pragma unroll
        for (int r = 0; r < 4; ++r) mr[rt][r] = -1e30f;
    }

    half8 bones;
    #pragma unroll
    for (int j = 0; j < 8; ++j) bones[j] = (_Float16)1.0f;

    // staging decomposition: thread loads K/V row sr, cols [sc..sc+3] and [sc+32..sc+35]
    const int sr = t >> 3;
    const int sc = (t & 7) * 4;
    float sinv[4];
    #pragma unroll
    for (int i = 0; i < 4; ++i) sinv[i] = exp2f(-(float)(sc + i) * LOG2B);

    const int NKT  = qt * 8 + 8;            // tiles the block stages
    const int nktw = qt * 8 + w * 2 + 2;    // tiles this wave computes

    for (int kt = 0; kt < NKT; ++kt) {
        const int kb0 = kt * 32;
        __syncthreads();
        {   // ---- stage K (RoPE, fp16) and V (transposed, fp16) ----
            const float* kp = kbase + (long)(kb0 + sr) * HD_ + sc;
            const float* vp = vbase + (long)(kb0 + sr) * HD_ + sc;
            float4 ka = *(const float4*)kp;
            float4 kc = *(const float4*)(kp + 32);
            float4 va = *(const float4*)vp;
            float4 vc = *(const float4*)(vp + 32);
            float kaa[4] = {ka.x, ka.y, ka.z, ka.w};
            float kcc[4] = {kc.x, kc.y, kc.z, kc.w};
            float vaa[4] = {va.x, va.y, va.z, va.w};
            float vcc[4] = {vc.x, vc.y, vc.z, vc.w};
            const float pos = (float)(p0 + kb0 + sr);
            half4 o0, o1;
            #pragma unroll
            for (int i = 0; i < 4; ++i) {
                float sn, cs; __sincosf(pos * sinv[i], &sn, &cs);
                o0[i] = (_Float16)(kaa[i] * cs - kcc[i] * sn);
                o1[i] = (_Float16)(kcc[i] * cs + kaa[i] * sn);
            }
            *(half4*)(&Kl[sr * KSTR + sc])      = o0;
            *(half4*)(&Kl[sr * KSTR + sc + 32]) = o1;
            #pragma unroll
            for (int i = 0; i < 4; ++i) {
                Vt[(sc + i) * VSTR + sr]      = (_Float16)vaa[i];
                Vt[(sc + 32 + i) * VSTR + sr] = (_Float16)vcc[i];
            }
        }
        __syncthreads();

        if (kt < nktw) {
            // ---- K B-fragments: lane n=kk holds K[kk][kt2*32 + lg*8 + j] ----
            half8 bk0[2], bk1[2];
            #pragma unroll
            for (int ct = 0; ct < 2; ++ct) {
                const _Float16* kr = &Kl[(ct * 16 + ln) * KSTR + lg * 8];
                bk0[ct] = *(const half8*)kr;
                bk1[ct] = *(const half8*)(kr + 32);
            }
            // ---- S = Q K^T ----
            floatx4 s[4][2];
            #pragma unroll
            for (int rt = 0; rt < 4; ++rt)
                #pragma unroll
                for (int ct = 0; ct < 2; ++ct) {
                    floatx4 acc = (floatx4){0.f, 0.f, 0.f, 0.f};
                    acc = __builtin_amdgcn_mfma_f32_16x16x32_f16(aq[rt][0], bk0[ct], acc, 0, 0, 0);
                    acc = __builtin_amdgcn_mfma_f32_16x16x32_f16(aq[rt][1], bk1[ct], acc, 0, 0, 0);
                    s[rt][ct] = acc;
                }
            // ---- causal mask (only diagonal-adjacent tiles) ----
            if (kb0 + 31 > qb) {
                #pragma unroll
                for (int rt = 0; rt < 4; ++rt)
                    #pragma unroll
                    for (int ct = 0; ct < 2; ++ct) {
                        const int kkc = kb0 + ct * 16 + ln;
                        #pragma unroll
                        for (int r = 0; r < 4; ++r) {
                            const int qq = qb + rt * 16 + lg * 4 + r;
                            if (kkc > qq) s[rt][ct][r] = -1e30f;
                        }
                    }
            }
            // ---- online softmax: DPP row-max, rescale, exp ----
            #pragma unroll
            for (int rt = 0; rt < 4; ++rt) {
                float alpha[4];
                #pragma unroll
                for (int r = 0; r < 4; ++r) {
                    float tm = rormax16(fmaxf(s[rt][0][r], s[rt][1][r]));
                    float mnew = fmaxf(mr[rt][r], tm);
                    alpha[r] = __expf(mr[rt][r] - mnew);
                    mr[rt][r] = mnew;
                }
                #pragma unroll
                for (int r = 0; r < 4; ++r) {
                    Ol[rt][r] *= alpha[r];
                    #pragma unroll
                    for (int dt = 0; dt < 4; ++dt) O[rt][dt][r] *= alpha[r];
                }
                // p = exp(s - m), write P tile (fp16) to this wave's LDS slab
                #pragma unroll
                for (int r = 0; r < 4; ++r) {
                    float p0v = __expf(s[rt][0][r] - mr[rt][r]);
                    float p1v = __expf(s[rt][1][r] - mr[rt][r]);
                    const int qloc = rt * 16 + lg * 4 + r;
                    Pl[w][qloc * PSTR + ln]      = (_Float16)p0v;
                    Pl[w][qloc * PSTR + 16 + ln] = (_Float16)p1v;
                }
            }
            // ---- PV: A = P (from LDS), B = V^T (from Vt) + ones-MFMA for l ----
            half8 ap[4], bv[4];
            #pragma unroll
            for (int rt = 0; rt < 4; ++rt)
                ap[rt] = *(const half8*)(&Pl[w][(rt * 16 + ln) * PSTR + lg * 8]);
            #pragma unroll
            for (int dt = 0; dt < 4; ++dt)
                bv[dt] = *(const half8*)(&Vt[(dt * 16 + ln) * VSTR + lg * 8]);
            #pragma unroll
            for (int rt = 0; rt < 4; ++rt) {
                #pragma unroll
                for (int dt = 0; dt < 4; ++dt)
                    O[rt][dt] = __builtin_amdgcn_mfma_f32_16x16x32_f16(ap[rt], bv[dt], O[rt][dt], 0, 0, 0);
                Ol[rt] = __builtin_amdgcn_mfma_f32_16x16x32_f16(ap[rt], bones, Ol[rt], 0, 0, 0);
            }
        }
    }

    // ---- epilogue: normalize and store ----
    #pragma unroll
    for (int rt = 0; rt < 4; ++rt) {
        float inv[4];
        #pragma unroll
        for (int r = 0; r < 4; ++r) inv[r] = 1.0f / Ol[rt][r];
        #pragma unroll
        for (int dt = 0; dt < 4; ++dt) {
            #pragma unroll
            for (int r = 0; r < 4; ++r) {
                const int qr = qb + rt * 16 + lg * 4 + r;
                outg[bhbase + (long)qr * HD_ + dt * 16 + ln] = O[rt][dt][r] * inv[r];
            }
        }
    }
}

extern "C" void kernel_launch(void* const* d_in, const int* in_sizes, int n_in,
                              void* d_out, int out_size, void* d_ws, size_t ws_size,
                              hipStream_t stream) {
    const float* q    = (const float*)d_in[0];
    const float* k    = (const float*)d_in[1];
    const float* v    = (const float*)d_in[2];
    const int*   sidx = (const int*)d_in[3];
    float*       out  = (float*)d_out;

    dim3 grid(B_ * NC_ * H_ * QT_);   // 1024 blocks: (b, n, h, qt)
    dim3 block(256);
    attn_mfma_f16<<<grid, block, 0, stream>>>(q, k, v, sidx, out);
}

// Round 3
// 284.576 us; speedup vs baseline: 4.8769x; 1.2518x over previous
//
#include <hip/hip_runtime.h>
#include <math.h>

typedef _Float16 half8 __attribute__((ext_vector_type(8)));
typedef _Float16 half4 __attribute__((ext_vector_type(4)));
typedef float    floatx4 __attribute__((ext_vector_type(4)));

#define B_   2
#define L_   8192
#define H_   16
#define D_   64
#define C_   1024
#define NC_  8
#define HD_  1024             // global row stride in floats
#define KSTR 72               // Kl row stride (f16)
#define VSTR 40               // Vt row stride (f16)
#define PSTR 40               // Pl row stride (f16)
#define LOG2B 0.41524101186098314f   // log2(10000)/32

__device__ __forceinline__ float rormax16(float v) {
    int x;
    x = __builtin_amdgcn_mov_dpp(__float_as_int(v), 0x121, 0xf, 0xf, true); v = fmaxf(v, __int_as_float(x));
    x = __builtin_amdgcn_mov_dpp(__float_as_int(v), 0x122, 0xf, 0xf, true); v = fmaxf(v, __int_as_float(x));
    x = __builtin_amdgcn_mov_dpp(__float_as_int(v), 0x124, 0xf, 0xf, true); v = fmaxf(v, __int_as_float(x));
    x = __builtin_amdgcn_mov_dpp(__float_as_int(v), 0x128, 0xf, 0xf, true); v = fmaxf(v, __int_as_float(x));
    return v;
}

__global__ __launch_bounds__(256, 2)
void attn_v3(const float* __restrict__ qg, const float* __restrict__ kg,
             const float* __restrict__ vg, const int* __restrict__ sidx,
             float* __restrict__ outg)
{
    __shared__ __align__(16) _Float16 Kl[32 * KSTR];     // K tile, RoPE'd, f16 [k][d]
    __shared__ __align__(16) _Float16 Vt[64 * VSTR];     // V tile, f16, transposed [dv][k]
    __shared__ __align__(16) _Float16 Pl[4][16 * PSTR];  // per-wave P slab (one strip at a time)

    const int t  = threadIdx.x;
    const int w  = t >> 6;         // wave 0..3
    const int lg = (t >> 4) & 3;   // 16-lane group
    const int ln = t & 15;

    const int bid = blockIdx.x;
    const int j  = bid & 3;        // sub-block (q fine offset) — every j has ~equal work
    const int h  = (bid >> 2) & 15;
    const int n  = (bid >> 6) & 7;
    const int b  = bid >> 9;

    const int p0   = sidx[0] + n * C_;       // absolute position of chunk row 0
    const int qoff = j * 64 + w * 16;        // wave's strip offset; strip s at qoff + s*256

    const long bhbase = ((long)b * L_ + (long)n * C_) * HD_ + (long)h * D_;
    const float* kbase = kg + bhbase;
    const float* vbase = vg + bhbase;

    // ---- Q fragments (A-layout) per strip, RoPE'd, f16 ----
    half8 aq[4][2];
    const int d0 = lg * 8;
    #pragma unroll
    for (int s = 0; s < 4; ++s) {
        const int qr = s * 256 + qoff + ln;
        const float* qp = qg + bhbase + (long)qr * HD_;
        float4 f0 = *(const float4*)(qp + d0);
        float4 f1 = *(const float4*)(qp + d0 + 4);
        float4 g0 = *(const float4*)(qp + d0 + 32);
        float4 g1 = *(const float4*)(qp + d0 + 36);
        float x[8] = {f0.x,f0.y,f0.z,f0.w,f1.x,f1.y,f1.z,f1.w};
        float y[8] = {g0.x,g0.y,g0.z,g0.w,g1.x,g1.y,g1.z,g1.w};
        const float pos = (float)(p0 + qr);
        #pragma unroll
        for (int jj = 0; jj < 8; ++jj) {
            float invf = exp2f(-(float)(d0 + jj) * LOG2B);
            float sn, cs; __sincosf(pos * invf, &sn, &cs);
            aq[s][0][jj] = (_Float16)(x[jj] * cs - y[jj] * sn);
            aq[s][1][jj] = (_Float16)(y[jj] * cs + x[jj] * sn);
        }
    }

    // ---- accumulators ----
    floatx4 O[4][4];     // [strip][dvt]; C-layout row = lg*4+reg, col = dvt*16+ln
    floatx4 Ol[4];       // row-sum via ones-MFMA
    float   mr[4][4];    // running max
    #pragma unroll
    for (int s = 0; s < 4; ++s) {
        Ol[s] = (floatx4){0.f,0.f,0.f,0.f};
        #pragma unroll
        for (int dt = 0; dt < 4; ++dt) O[s][dt] = (floatx4){0.f,0.f,0.f,0.f};
        #pragma unroll
        for (int r = 0; r < 4; ++r) mr[s][r] = -1e30f;
    }
    half8 bones;
    #pragma unroll
    for (int jj = 0; jj < 8; ++jj) bones[jj] = (_Float16)1.0f;

    // ---- staging decomposition ----
    const int sr = t >> 3;           // K: row 0..31
    const int sc = (t & 7) * 4;      // K: col quad
    float sinvk[4];
    #pragma unroll
    for (int i = 0; i < 4; ++i) sinvk[i] = exp2f(-(float)(sc + i) * LOG2B);
    const int vc = t & 31;           // V: dv-pair index (dv = 2vc, 2vc+1)
    const int vr = (t >> 5) * 4;     // V: k-row base 0..28

    const int NKT = ((831 + j * 64) >> 5) + 1;   // block staging tiles (26..32)
    int nkt_s[4];
    #pragma unroll
    for (int s = 0; s < 4; ++s) nkt_s[s] = ((s * 256 + qoff + 15) >> 5) + 1;

    // ---- prefetch tile 0 into registers ----
    float4 kp0, kp1; float2 vp0, vp1, vp2, vp3;
    {
        const float* kp = kbase + (long)sr * HD_ + sc;
        kp0 = *(const float4*)kp; kp1 = *(const float4*)(kp + 32);
        const float* vp = vbase + (long)vr * HD_ + 2 * vc;
        vp0 = *(const float2*)vp;           vp1 = *(const float2*)(vp + HD_);
        vp2 = *(const float2*)(vp + 2*HD_); vp3 = *(const float2*)(vp + 3*HD_);
    }

    for (int kt = 0; kt < NKT; ++kt) {
        const int kb0 = kt * 32;
        __syncthreads();   // previous tile fully consumed
        {   // ---- write staged tile: RoPE K, repack V (b64 writes) ----
            const float pos = (float)(p0 + kb0 + sr);
            float ka[4] = {kp0.x,kp0.y,kp0.z,kp0.w};
            float kc[4] = {kp1.x,kp1.y,kp1.z,kp1.w};
            half4 o0, o1;
            #pragma unroll
            for (int i = 0; i < 4; ++i) {
                float sn, cs; __sincosf(pos * sinvk[i], &sn, &cs);
                o0[i] = (_Float16)(ka[i] * cs - kc[i] * sn);
                o1[i] = (_Float16)(kc[i] * cs + ka[i] * sn);
            }
            *(half4*)(&Kl[sr * KSTR + sc])      = o0;
            *(half4*)(&Kl[sr * KSTR + sc + 32]) = o1;
            half4 va, vb;
            va[0] = (_Float16)vp0.x; va[1] = (_Float16)vp1.x; va[2] = (_Float16)vp2.x; va[3] = (_Float16)vp3.x;
            vb[0] = (_Float16)vp0.y; vb[1] = (_Float16)vp1.y; vb[2] = (_Float16)vp2.y; vb[3] = (_Float16)vp3.y;
            *(half4*)(&Vt[(2 * vc)     * VSTR + vr]) = va;
            *(half4*)(&Vt[(2 * vc + 1) * VSTR + vr]) = vb;
        }
        if (kt + 1 < NKT) {   // ---- prefetch next tile (lands during compute) ----
            const int kb1 = kb0 + 32;
            const float* kp = kbase + (long)(kb1 + sr) * HD_ + sc;
            kp0 = *(const float4*)kp; kp1 = *(const float4*)(kp + 32);
            const float* vp = vbase + (long)(kb1 + vr) * HD_ + 2 * vc;
            vp0 = *(const float2*)vp;           vp1 = *(const float2*)(vp + HD_);
            vp2 = *(const float2*)(vp + 2*HD_); vp3 = *(const float2*)(vp + 3*HD_);
        }
        __syncthreads();   // tile visible

        // ---- fragments shared across strips ----
        half8 bk0[2], bk1[2], bv[4];
        #pragma unroll
        for (int ct = 0; ct < 2; ++ct) {
            const _Float16* kr = &Kl[(ct * 16 + ln) * KSTR + lg * 8];
            bk0[ct] = *(const half8*)kr;
            bk1[ct] = *(const half8*)(kr + 32);
        }
        #pragma unroll
        for (int dt = 0; dt < 4; ++dt)
            bv[dt] = *(const half8*)(&Vt[(dt * 16 + ln) * VSTR + lg * 8]);

        #pragma unroll
        for (int s = 0; s < 4; ++s) {
            if (kt >= nkt_s[s]) continue;          // wave-uniform
            const int qs = s * 256 + qoff;

            floatx4 sacc[2];
            #pragma unroll
            for (int ct = 0; ct < 2; ++ct) {
                floatx4 acc = (floatx4){0.f,0.f,0.f,0.f};
                acc = __builtin_amdgcn_mfma_f32_16x16x32_f16(aq[s][0], bk0[ct], acc, 0, 0, 0);
                acc = __builtin_amdgcn_mfma_f32_16x16x32_f16(aq[s][1], bk1[ct], acc, 0, 0, 0);
                sacc[ct] = acc;
            }
            if (kb0 + 31 > qs) {                   // diagonal tile: mask
                #pragma unroll
                for (int ct = 0; ct < 2; ++ct) {
                    const int kkc = kb0 + ct * 16 + ln;
                    #pragma unroll
                    for (int r = 0; r < 4; ++r)
                        if (kkc > qs + lg * 4 + r) sacc[ct][r] = -1e30f;
                }
            }
            float alpha[4];
            #pragma unroll
            for (int r = 0; r < 4; ++r) {
                float tm   = rormax16(fmaxf(sacc[0][r], sacc[1][r]));
                float mnew = fmaxf(mr[s][r], tm);
                alpha[r]   = __expf(mr[s][r] - mnew);
                mr[s][r]   = mnew;
            }
            #pragma unroll
            for (int r = 0; r < 4; ++r) {
                Ol[s][r] *= alpha[r];
                #pragma unroll
                for (int dt = 0; dt < 4; ++dt) O[s][dt][r] *= alpha[r];
            }
            #pragma unroll
            for (int r = 0; r < 4; ++r) {
                float pa = __expf(sacc[0][r] - mr[s][r]);
                float pb = __expf(sacc[1][r] - mr[s][r]);
                const int qloc = lg * 4 + r;
                Pl[w][qloc * PSTR + ln]      = (_Float16)pa;
                Pl[w][qloc * PSTR + 16 + ln] = (_Float16)pb;
            }
            half8 ap = *(const half8*)(&Pl[w][ln * PSTR + lg * 8]);
            #pragma unroll
            for (int dt = 0; dt < 4; ++dt)
                O[s][dt] = __builtin_amdgcn_mfma_f32_16x16x32_f16(ap, bv[dt], O[s][dt], 0, 0, 0);
            Ol[s] = __builtin_amdgcn_mfma_f32_16x16x32_f16(ap, bones, Ol[s], 0, 0, 0);
        }
    }

    // ---- epilogue ----
    #pragma unroll
    for (int s = 0; s < 4; ++s) {
        const int qs = s * 256 + qoff;
        float inv[4];
        #pragma unroll
        for (int r = 0; r < 4; ++r) inv[r] = 1.0f / Ol[s][r];
        #pragma unroll
        for (int dt = 0; dt < 4; ++dt) {
            #pragma unroll
            for (int r = 0; r < 4; ++r) {
                const int qr = qs + lg * 4 + r;
                outg[bhbase + (long)qr * HD_ + dt * 16 + ln] = O[s][dt][r] * inv[r];
            }
        }
    }
}

extern "C" void kernel_launch(void* const* d_in, const int* in_sizes, int n_in,
                              void* d_out, int out_size, void* d_ws, size_t ws_size,
                              hipStream_t stream) {
    const float* q    = (const float*)d_in[0];
    const float* k    = (const float*)d_in[1];
    const float* v    = (const float*)d_in[2];
    const int*   sidx = (const int*)d_in[3];
    float*       out  = (float*)d_out;

    dim3 grid(B_ * NC_ * H_ * 4);   // 1024 blocks: (b, n, h, j)
    dim3 block(256);
    attn_v3<<<grid, block, 0, stream>>>(q, k, v, sidx, out);
}